// Round 12
// baseline (576.446 us; speedup 1.0000x reference)
//
#include <hip/hip_runtime.h>
#include <cstdint>

// SpikingCNN: B=8192, D=784, H=128, O=10, T=20, beta=0.9, thr=1.0
// R12 = R11 with the workspace overlap FIXED: weight planes are 614400 B
// (3*128*800*2), not 480000 B. r11's m32 buffer overlapped wp plane-2
// (h>=44) -> NaN weights -> no spikes -> out==0 (stub-level absmax).
//  P : split w1 -> 3 exact bf16 planes [3][128][800] (Dekker, products exact).
//  S : spikegen -> BITMASK m32[flatrow][25 words]; thread per (b,word),
//      t-loop inside (x read once). Pure VALU streaming, no LDS/barriers.
//      RNG (r9/r10-verified): (x0,x1)=threefry2x32((0,42),(0,n)),
//      n=t*B*D+b*D+d, bits=x0^x1, u=bitcast((bits>>9)|0x3f800000)-1, u<p.
//  G : LDS-free, barrier-free MFMA GEMM: A-frags expanded in-register from
//      mask bytes; B-frags from weight planes (L2-resident). Accumulation
//      order identical to r10 (ko-chunks of 32, planes p=0,1,2 into same acc).
//  B1: LIF1, 16 lanes/row (same per-h op order as r9/r10), packs bitmasks.
//  B2: layer-2 ascending-h chain + LIF2 (unchanged, r9-verified).

#define T_STEPS 20
#define B_SZ   8192
#define D_SZ   784
#define H_SZ   128
#define O_SZ   10
#define CUR1_BYTES  83886080u                 // 20*8192*128*4
#define MASKS_OFF   83886080u                 // B1 masks: 20*8192*4*4 = 655360
#define WP_OFF      84541440u                 // weight planes: 3*128*800*2 = 614400
#define M32_OFF     85155840u                 // = WP_OFF + 614400 ; m32: 16384000 B

typedef __attribute__((ext_vector_type(8))) short short8;
typedef __attribute__((ext_vector_type(4))) float f32x4;
typedef unsigned short ushort_t;

__device__ __forceinline__ uint32_t rotl32(uint32_t x, uint32_t d) {
  return (x << d) | (x >> (32u - d));
}

// JAX threefry2x32, key = (0, 42) from jax.random.key(42).
__device__ __forceinline__ void threefry_0_42(uint32_t c0, uint32_t c1,
                                              uint32_t& o0, uint32_t& o1) {
  const uint32_t ks0 = 0u;
  const uint32_t ks1 = 42u;
  const uint32_t ks2 = 0u ^ 42u ^ 0x1BD11BDAu;
  uint32_t x0 = c0 + ks0;
  uint32_t x1 = c1 + ks1;
#define TF_R(rot) { x0 += x1; x1 = rotl32(x1, rot); x1 ^= x0; }
  TF_R(13u) TF_R(15u) TF_R(26u) TF_R(6u)
  x0 += ks1; x1 += ks2 + 1u;
  TF_R(17u) TF_R(29u) TF_R(16u) TF_R(24u)
  x0 += ks2; x1 += ks0 + 2u;
  TF_R(13u) TF_R(15u) TF_R(26u) TF_R(6u)
  x0 += ks0; x1 += ks1 + 3u;
  TF_R(17u) TF_R(29u) TF_R(16u) TF_R(24u)
  x0 += ks1; x1 += ks2 + 4u;
  TF_R(13u) TF_R(15u) TF_R(26u) TF_R(6u)
  x0 += ks2; x1 += ks0 + 5u;
#undef TF_R
  o0 = x0; o1 = x1;
}

__device__ __forceinline__ float tf_uniform(uint32_t bits) {
  return __uint_as_float((bits >> 9) | 0x3f800000u) - 1.0f;
}

__device__ __forceinline__ uint32_t rne_bf16_bits(float f) {
  uint32_t u = __float_as_uint(f);
  return (u + 0x7fffu + ((u >> 16) & 1u)) & 0xffff0000u;
}

// ---------------------------------------------------------------------------
// P: split w1 f32 [128][784] into 3 exact bf16 planes [128][800] (k-padded 0).
// ---------------------------------------------------------------------------
__global__ __launch_bounds__(256) void split_w1(
    const float* __restrict__ w1, ushort_t* __restrict__ wp) {
  const int h = blockIdx.x;
  for (int k = threadIdx.x; k < 800; k += 256) {
    float w = (k < D_SZ) ? w1[h * D_SZ + k] : 0.0f;
    uint32_t hb = rne_bf16_bits(w);
    float hi = __uint_as_float(hb);
    float r1 = w - hi;                      // exact
    uint32_t mb = rne_bf16_bits(r1);
    float mid = __uint_as_float(mb);
    float lo = r1 - mid;                    // exact, <=8 significant bits
    uint32_t lb = __float_as_uint(lo);
    wp[0 * 102400 + h * 800 + k] = (ushort_t)(hb >> 16);
    wp[1 * 102400 + h * 800 + k] = (ushort_t)(mb >> 16);
    wp[2 * 102400 + h * 800 + k] = (ushort_t)(lb >> 16);
  }
}

// ---------------------------------------------------------------------------
// S: spikegen -> bitmasks. Thread g -> (b = g/25, word w = g%25); t-loop of 20.
// m32[(t*8192+b)*25 + w], bit j = spike at d = w*32+j. Coalesced stores.
// ---------------------------------------------------------------------------
__global__ __launch_bounds__(256) void spikegen_bits(
    const float* __restrict__ x, uint32_t* __restrict__ m32) {
  const int g = blockIdx.x * 256 + threadIdx.x;   // 0..204799
  const int b = g / 25;
  const int w = g - b * 25;
  const int d0 = w << 5;

  float pr[32];
  {
    const float* xr = x + (size_t)b * D_SZ + d0;
    const int nv = (w == 24) ? 4 : 8;             // word 24: only 16 valid d
#pragma unroll
    for (int q = 0; q < 8; ++q) {
      float4 v;
      if (q < nv) v = *(const float4*)&xr[q * 4];
      else        v = (float4){0.f, 0.f, 0.f, 0.f};   // p=0 -> never spikes
      pr[q * 4 + 0] = v.x; pr[q * 4 + 1] = v.y;
      pr[q * 4 + 2] = v.z; pr[q * 4 + 3] = v.w;
    }
  }

  const uint32_t bw = (uint32_t)b * 784u + (uint32_t)d0;
#pragma unroll 1
  for (int t = 0; t < T_STEPS; ++t) {
    const uint32_t nb = (uint32_t)t * 6422528u + bw;
    uint32_t word = 0u;
#pragma unroll
    for (int j = 0; j < 32; ++j) {
      uint32_t o0, o1;
      threefry_0_42(0u, nb + (uint32_t)j, o0, o1);
      word |= (tf_uniform(o0 ^ o1) < pr[j]) ? (1u << j) : 0u;
    }
    m32[(size_t)(t * B_SZ + b) * 25 + w] = word;
  }
}

// ---------------------------------------------------------------------------
// G: LDS-free barrier-free MFMA GEMM. grid 1280 x 256 (4 waves = 2x2
// quadrants of a 128x128 C-tile). 25 chunks of k=32; per wave/chunk:
// 4 mask dwords -> in-register A-frag expansion, 12 B-frag dwordx4 loads,
// 48 mfma. Same accumulation order as r10 (absmax 0.0 verified).
// ---------------------------------------------------------------------------
__global__ __launch_bounds__(256) void gemm1_mfma(
    const ushort_t* __restrict__ wp, const uint32_t* __restrict__ m32,
    const float* __restrict__ b1, float* __restrict__ cur1) {
  const int tid  = threadIdx.x;
  const int row0 = blockIdx.x << 7;
  const int wave = tid >> 6, lane = tid & 63;
  const int wr0  = (wave >> 1) << 6;
  const int wc0  = (wave & 1) << 6;
  const int lm   = lane & 15, quad = lane >> 4;
  const int qsh  = quad << 3;          // bit shift AND k-offset (quad*8)

  f32x4 acc[4][4];
#pragma unroll
  for (int m = 0; m < 4; ++m)
#pragma unroll
    for (int nn = 0; nn < 4; ++nn) acc[m][nn] = (f32x4){0.f, 0.f, 0.f, 0.f};

  // mask-word base for this lane's A rows (rows wr0+m*16+lm)
  const uint32_t* mrow = m32 + (size_t)(row0 + wr0 + lm) * 25;
  // weight base for this lane's B cols (col wc0+nn*16+lm), k-offset quad*8
  const ushort_t* wbase = wp + (size_t)(wc0 + lm) * 800 + qsh;

  for (int ko = 0; ko < 25; ++ko) {
    short8 a[4];
#pragma unroll
    for (int m = 0; m < 4; ++m) {
      uint32_t word = mrow[m * 400 + ko];          // row stride 16*25=400
      uint32_t byte = (word >> qsh) & 0xffu;
      short8 av;
#pragma unroll
      for (int j = 0; j < 8; ++j)
        av[j] = (short)(((byte >> j) & 1u) ? 0x3F80 : 0);
      a[m] = av;
    }
    const int kof = ko << 5;
#pragma unroll
    for (int p = 0; p < 3; ++p) {
#pragma unroll
      for (int nn = 0; nn < 4; ++nn) {
        short8 bf = *(const short8*)&wbase[p * 102400 + nn * 16 * 800 + kof];
#pragma unroll
        for (int m = 0; m < 4; ++m)
          acc[m][nn] = __builtin_amdgcn_mfma_f32_16x16x32_bf16(
              a[m], bf, acc[m][nn], 0, 0, 0);
      }
    }
  }

  // epilogue: C/D layout col=lane&15, row=quad*4+reg (r10-verified)
#pragma unroll
  for (int nn = 0; nn < 4; ++nn) {
    int col = wc0 + nn * 16 + lm;
    float bias = b1[col];
#pragma unroll
    for (int m = 0; m < 4; ++m) {
#pragma unroll
      for (int r = 0; r < 4; ++r) {
        int grow = row0 + wr0 + m * 16 + quad * 4 + r;
        cur1[(size_t)grow * H_SZ + col] = acc[m][nn][r] + bias;
      }
    }
  }
}

// ---------------------------------------------------------------------------
// B1: LIF1, 16 lanes/row; lane s owns h = s*8..s*8+7 (contiguous, coalesced).
// Identical per-h op order to r9/r10. Packs 128-bit mask -> 4 u32 words
// (bit index == h - 32w), words gathered so lanes s=0..3 store coalesced.
// ---------------------------------------------------------------------------
__global__ __launch_bounds__(256) void lif1_spikes(
    const float* __restrict__ cur1, uint32_t* __restrict__ masks) {
#pragma clang fp contract(off)
  const int g    = blockIdx.x * 256 + threadIdx.x;  // 0..131071
  const int row  = g >> 4;
  const int s    = g & 15;
  const int lane = threadIdx.x & 63;

  float mem[8];
#pragma unroll
  for (int i = 0; i < 8; ++i) mem[i] = 0.0f;

  for (int t = 0; t < T_STEPS; ++t) {
    const float* base = cur1 + ((size_t)t * B_SZ + row) * H_SZ + s * 8;
    float4 c0 = *(const float4*)base;
    float4 c1 = *(const float4*)(base + 4);
    float cv[8] = {c0.x, c0.y, c0.z, c0.w, c1.x, c1.y, c1.z, c1.w};

    uint32_t bits8 = 0u;
#pragma unroll
    for (int q = 0; q < 8; ++q) {
      float m = mem[q];
      float reset = (m > 1.0f) ? 1.0f : 0.0f;
      m = 0.9f * m;
      m = m + cv[q];
      m = m - reset;
      mem[q] = m;
      bits8 |= (m > 1.0f) ? (1u << q) : 0u;
    }
    // word w = s>>2 built from subs 4w..4w+3; this sub's byte pos = s&3
    uint32_t part = bits8 << ((s & 3) * 8);
    part |= __shfl_xor(part, 1);
    part |= __shfl_xor(part, 2);
    // lanes s=0..3 fetch word s (held by lane group base + 4s)
    uint32_t myw = __shfl(part, (lane & ~15) + 4 * (s & 3));
    if (s < 4)
      masks[((size_t)t * B_SZ + row) * 4 + s] = myw;
  }
}

// ---------------------------------------------------------------------------
// B2: layer-2 ascending-h add chain + LIF2 (unchanged from r9/r10).
// ---------------------------------------------------------------------------
__global__ __launch_bounds__(320) void lif2_seq(
    const float* __restrict__ w2, const float* __restrict__ b2,
    const uint32_t* __restrict__ masks, float* __restrict__ out) {
#pragma clang fp contract(off)
  __shared__ __align__(16) float sW2[O_SZ][H_SZ];
  const int tid = threadIdx.x;
  for (int i = tid; i < O_SZ * H_SZ; i += 320)
    sW2[i >> 7][i & 127] = w2[i];
  __syncthreads();

  const int wave = tid >> 6;
  const int lane = tid & 63;
  const int row  = ((blockIdx.x >> 1) << 6) + lane;
  const int o    = (blockIdx.x & 1) * 5 + wave;
  const float bias = b2[o];

  float mem2 = 0.0f;
  int cnt = 0;
  const uint4* mbase = (const uint4*)masks;

  for (int t = 0; t < T_STEPS; ++t) {
    uint4 m = mbase[(size_t)t * B_SZ + row];
    uint32_t mw[4] = {m.x, m.y, m.z, m.w};
    float acc = 0.0f;
#pragma unroll
    for (int w = 0; w < 4; ++w) {
#pragma unroll
      for (int hc = 0; hc < 8; ++hc) {
        float4 wv = *(const float4*)&sW2[o][w * 32 + hc * 4];
        float vv[4] = {wv.x, wv.y, wv.z, wv.w};
#pragma unroll
        for (int bb = 0; bb < 4; ++bb) {
          float val = ((mw[w] >> (hc * 4 + bb)) & 1u) ? vv[bb] : 0.0f;
          acc = acc + val;
        }
      }
    }
    float c2 = acc + bias;
    float reset = (mem2 > 1.0f) ? 1.0f : 0.0f;
    mem2 = 0.9f * mem2;
    mem2 = mem2 + c2;
    mem2 = mem2 - reset;
    cnt += (mem2 > 1.0f) ? 1 : 0;
  }
  out[row * O_SZ + o] = (float)cnt / 20.0f;
}

extern "C" void kernel_launch(void* const* d_in, const int* in_sizes, int n_in,
                              void* d_out, int out_size, void* d_ws, size_t ws_size,
                              hipStream_t stream) {
  const float* x   = (const float*)d_in[0];  // [8192,784]
  const float* w1  = (const float*)d_in[1];  // [128,784]
  const float* b1  = (const float*)d_in[2];  // [128]
  const float* w2  = (const float*)d_in[3];  // [10,128]
  const float* b2  = (const float*)d_in[4];  // [10]
  float* out  = (float*)d_out;               // [8192,10]
  float*    cur1  = (float*)d_ws;
  uint32_t* masks = (uint32_t*)((char*)d_ws + MASKS_OFF);
  ushort_t* wp    = (ushort_t*)((char*)d_ws + WP_OFF);
  uint32_t* m32   = (uint32_t*)((char*)d_ws + M32_OFF);

  split_w1     <<<dim3(128),  dim3(256), 0, stream>>>(w1, wp);
  spikegen_bits<<<dim3(800),  dim3(256), 0, stream>>>(x, m32);
  gemm1_mfma   <<<dim3(1280), dim3(256), 0, stream>>>(wp, m32, b1, cur1);
  lif1_spikes  <<<dim3(512),  dim3(256), 0, stream>>>(cur1, masks);
  lif2_seq     <<<dim3(256),  dim3(320), 0, stream>>>(w2, b2, masks, out);
}

// Round 13
// 496.860 us; speedup vs baseline: 1.1602x; 1.1602x over previous
//
#include <hip/hip_runtime.h>
#include <cstdint>

// SpikingCNN: B=8192, D=784, H=128, O=10, T=20, beta=0.9, thr=1.0
// R13 = R12 with spikegen restructured for occupancy:
//  - thread per (t,b,word): 4.096M threads, 16000 blocks (62.5 blocks/CU,
//    <2% imbalance; r12 had 800 blocks -> 19.9% occupancy, VALU 73%).
//  - integer-space bernoulli: spike <=> (bits>>9) < ceil(p*2^23)  (exact
//    for all p in [0,1): u=(bits>>9)*2^-23 exact, p*2^23 exact (exp shift),
//    integer v < ceil(y) <=> v < y). Saves or+sub+fcmp per element.
//  P : split w1 -> 3 exact bf16 planes [3][128][800] (Dekker).
//  G : LDS-free barrier-free MFMA GEMM (r10-verified order, absmax 0.0).
//  B1: LIF1 16 lanes/row -> spike bitmasks.  B2: ascending-h chain + LIF2.
//  RNG (r9-verified): (x0,x1)=threefry2x32((0,42),(0,n)), n=t*6422528+b*784+d,
//  bits=x0^x1.

#define T_STEPS 20
#define B_SZ   8192
#define D_SZ   784
#define H_SZ   128
#define O_SZ   10
#define CUR1_BYTES  83886080u                 // 20*8192*128*4
#define MASKS_OFF   83886080u                 // B1 masks: 20*8192*4*4 = 655360
#define WP_OFF      84541440u                 // weight planes: 3*128*800*2 = 614400
#define M32_OFF     85155840u                 // = WP_OFF + 614400 ; m32: 16384000 B

typedef __attribute__((ext_vector_type(8))) short short8;
typedef __attribute__((ext_vector_type(4))) float f32x4;
typedef unsigned short ushort_t;

__device__ __forceinline__ uint32_t rotl32(uint32_t x, uint32_t d) {
  return (x << d) | (x >> (32u - d));
}

// JAX threefry2x32, key = (0, 42) from jax.random.key(42).
__device__ __forceinline__ void threefry_0_42(uint32_t c0, uint32_t c1,
                                              uint32_t& o0, uint32_t& o1) {
  const uint32_t ks0 = 0u;
  const uint32_t ks1 = 42u;
  const uint32_t ks2 = 0u ^ 42u ^ 0x1BD11BDAu;
  uint32_t x0 = c0 + ks0;
  uint32_t x1 = c1 + ks1;
#define TF_R(rot) { x0 += x1; x1 = rotl32(x1, rot); x1 ^= x0; }
  TF_R(13u) TF_R(15u) TF_R(26u) TF_R(6u)
  x0 += ks1; x1 += ks2 + 1u;
  TF_R(17u) TF_R(29u) TF_R(16u) TF_R(24u)
  x0 += ks2; x1 += ks0 + 2u;
  TF_R(13u) TF_R(15u) TF_R(26u) TF_R(6u)
  x0 += ks0; x1 += ks1 + 3u;
  TF_R(17u) TF_R(29u) TF_R(16u) TF_R(24u)
  x0 += ks1; x1 += ks2 + 4u;
  TF_R(13u) TF_R(15u) TF_R(26u) TF_R(6u)
  x0 += ks2; x1 += ks0 + 5u;
#undef TF_R
  o0 = x0; o1 = x1;
}

__device__ __forceinline__ uint32_t rne_bf16_bits(float f) {
  uint32_t u = __float_as_uint(f);
  return (u + 0x7fffu + ((u >> 16) & 1u)) & 0xffff0000u;
}

// ---------------------------------------------------------------------------
// P: split w1 f32 [128][784] into 3 exact bf16 planes [128][800] (k-padded 0).
// ---------------------------------------------------------------------------
__global__ __launch_bounds__(256) void split_w1(
    const float* __restrict__ w1, ushort_t* __restrict__ wp) {
  const int h = blockIdx.x;
  for (int k = threadIdx.x; k < 800; k += 256) {
    float w = (k < D_SZ) ? w1[h * D_SZ + k] : 0.0f;
    uint32_t hb = rne_bf16_bits(w);
    float hi = __uint_as_float(hb);
    float r1 = w - hi;                      // exact
    uint32_t mb = rne_bf16_bits(r1);
    float mid = __uint_as_float(mb);
    float lo = r1 - mid;                    // exact, <=8 significant bits
    uint32_t lb = __float_as_uint(lo);
    wp[0 * 102400 + h * 800 + k] = (ushort_t)(hb >> 16);
    wp[1 * 102400 + h * 800 + k] = (ushort_t)(mb >> 16);
    wp[2 * 102400 + h * 800 + k] = (ushort_t)(lb >> 16);
  }
}

// ---------------------------------------------------------------------------
// S: spikegen -> bitmasks. Thread g -> (tb = g/25, word w = g%25),
// tb = t*8192 + b. One 32-bit mask word per thread; store at m32[g]
// (coalesced). Integer-threshold compare (exactness proven in header).
// ---------------------------------------------------------------------------
__global__ __launch_bounds__(256) void spikegen_bits(
    const float* __restrict__ x, uint32_t* __restrict__ m32) {
  const int g  = blockIdx.x * 256 + threadIdx.x;  // 0..4,095,999
  const int tb = g / 25;
  const int w  = g - tb * 25;
  const int b  = tb & 8191;
  const int d0 = w << 5;

  uint32_t T[32];
  {
    const float* xr = x + (size_t)b * D_SZ + d0;
    const int nv = (w == 24) ? 4 : 8;             // word 24: only 16 valid d
#pragma unroll
    for (int q = 0; q < 8; ++q) {
      float4 v;
      if (q < nv) v = *(const float4*)&xr[q * 4];
      else        v = (float4){0.f, 0.f, 0.f, 0.f};   // p=0 -> T=0 -> no spike
      T[q * 4 + 0] = (uint32_t)__builtin_ceilf(v.x * 8388608.0f);
      T[q * 4 + 1] = (uint32_t)__builtin_ceilf(v.y * 8388608.0f);
      T[q * 4 + 2] = (uint32_t)__builtin_ceilf(v.z * 8388608.0f);
      T[q * 4 + 3] = (uint32_t)__builtin_ceilf(v.w * 8388608.0f);
    }
  }

  // n = t*6422528 + b*784 + d = tb*784 - b*784*0 ... compute directly:
  const uint32_t nb = (uint32_t)(tb >> 13) * 6422528u + (uint32_t)b * 784u +
                      (uint32_t)d0;
  uint32_t word = 0u;
#pragma unroll
  for (int j = 0; j < 32; ++j) {
    uint32_t o0, o1;
    threefry_0_42(0u, nb + (uint32_t)j, o0, o1);
    word |= (((o0 ^ o1) >> 9) < T[j]) ? (1u << j) : 0u;
  }
  m32[g] = word;
}

// ---------------------------------------------------------------------------
// G: LDS-free barrier-free MFMA GEMM. grid 1280 x 256 (4 waves = 2x2
// quadrants of a 128x128 C-tile). 25 chunks of k=32; per wave/chunk:
// 4 mask dwords -> in-register A-frag expansion, 12 B-frag dwordx4 loads,
// 48 mfma. Same accumulation order as r10 (absmax 0.0 verified).
// ---------------------------------------------------------------------------
__global__ __launch_bounds__(256) void gemm1_mfma(
    const ushort_t* __restrict__ wp, const uint32_t* __restrict__ m32,
    const float* __restrict__ b1, float* __restrict__ cur1) {
  const int tid  = threadIdx.x;
  const int row0 = blockIdx.x << 7;
  const int wave = tid >> 6, lane = tid & 63;
  const int wr0  = (wave >> 1) << 6;
  const int wc0  = (wave & 1) << 6;
  const int lm   = lane & 15, quad = lane >> 4;
  const int qsh  = quad << 3;          // bit shift AND k-offset (quad*8)

  f32x4 acc[4][4];
#pragma unroll
  for (int m = 0; m < 4; ++m)
#pragma unroll
    for (int nn = 0; nn < 4; ++nn) acc[m][nn] = (f32x4){0.f, 0.f, 0.f, 0.f};

  const uint32_t* mrow = m32 + (size_t)(row0 + wr0 + lm) * 25;
  const ushort_t* wbase = wp + (size_t)(wc0 + lm) * 800 + qsh;

  for (int ko = 0; ko < 25; ++ko) {
    short8 a[4];
#pragma unroll
    for (int m = 0; m < 4; ++m) {
      uint32_t word = mrow[m * 400 + ko];          // row stride 16*25=400
      uint32_t byte = (word >> qsh) & 0xffu;
      short8 av;
#pragma unroll
      for (int j = 0; j < 8; ++j)
        av[j] = (short)(((byte >> j) & 1u) ? 0x3F80 : 0);
      a[m] = av;
    }
    const int kof = ko << 5;
#pragma unroll
    for (int p = 0; p < 3; ++p) {
#pragma unroll
      for (int nn = 0; nn < 4; ++nn) {
        short8 bf = *(const short8*)&wbase[p * 102400 + nn * 16 * 800 + kof];
#pragma unroll
        for (int m = 0; m < 4; ++m)
          acc[m][nn] = __builtin_amdgcn_mfma_f32_16x16x32_bf16(
              a[m], bf, acc[m][nn], 0, 0, 0);
      }
    }
  }

  // epilogue: C/D layout col=lane&15, row=quad*4+reg (r10-verified)
#pragma unroll
  for (int nn = 0; nn < 4; ++nn) {
    int col = wc0 + nn * 16 + lm;
    float bias = b1[col];
#pragma unroll
    for (int m = 0; m < 4; ++m) {
#pragma unroll
      for (int r = 0; r < 4; ++r) {
        int grow = row0 + wr0 + m * 16 + quad * 4 + r;
        cur1[(size_t)grow * H_SZ + col] = acc[m][nn][r] + bias;
      }
    }
  }
}

// ---------------------------------------------------------------------------
// B1: LIF1, 16 lanes/row; lane s owns h = s*8..s*8+7. Identical per-h op
// order to r9/r10. Packs 128-bit mask -> 4 u32 words, coalesced stores.
// ---------------------------------------------------------------------------
__global__ __launch_bounds__(256) void lif1_spikes(
    const float* __restrict__ cur1, uint32_t* __restrict__ masks) {
#pragma clang fp contract(off)
  const int g    = blockIdx.x * 256 + threadIdx.x;  // 0..131071
  const int row  = g >> 4;
  const int s    = g & 15;
  const int lane = threadIdx.x & 63;

  float mem[8];
#pragma unroll
  for (int i = 0; i < 8; ++i) mem[i] = 0.0f;

  for (int t = 0; t < T_STEPS; ++t) {
    const float* base = cur1 + ((size_t)t * B_SZ + row) * H_SZ + s * 8;
    float4 c0 = *(const float4*)base;
    float4 c1 = *(const float4*)(base + 4);
    float cv[8] = {c0.x, c0.y, c0.z, c0.w, c1.x, c1.y, c1.z, c1.w};

    uint32_t bits8 = 0u;
#pragma unroll
    for (int q = 0; q < 8; ++q) {
      float m = mem[q];
      float reset = (m > 1.0f) ? 1.0f : 0.0f;
      m = 0.9f * m;
      m = m + cv[q];
      m = m - reset;
      mem[q] = m;
      bits8 |= (m > 1.0f) ? (1u << q) : 0u;
    }
    uint32_t part = bits8 << ((s & 3) * 8);
    part |= __shfl_xor(part, 1);
    part |= __shfl_xor(part, 2);
    uint32_t myw = __shfl(part, (lane & ~15) + 4 * (s & 3));
    if (s < 4)
      masks[((size_t)t * B_SZ + row) * 4 + s] = myw;
  }
}

// ---------------------------------------------------------------------------
// B2: layer-2 ascending-h add chain + LIF2 (unchanged from r9/r10).
// ---------------------------------------------------------------------------
__global__ __launch_bounds__(320) void lif2_seq(
    const float* __restrict__ w2, const float* __restrict__ b2,
    const uint32_t* __restrict__ masks, float* __restrict__ out) {
#pragma clang fp contract(off)
  __shared__ __align__(16) float sW2[O_SZ][H_SZ];
  const int tid = threadIdx.x;
  for (int i = tid; i < O_SZ * H_SZ; i += 320)
    sW2[i >> 7][i & 127] = w2[i];
  __syncthreads();

  const int wave = tid >> 6;
  const int lane = tid & 63;
  const int row  = ((blockIdx.x >> 1) << 6) + lane;
  const int o    = (blockIdx.x & 1) * 5 + wave;
  const float bias = b2[o];

  float mem2 = 0.0f;
  int cnt = 0;
  const uint4* mbase = (const uint4*)masks;

  for (int t = 0; t < T_STEPS; ++t) {
    uint4 m = mbase[(size_t)t * B_SZ + row];
    uint32_t mw[4] = {m.x, m.y, m.z, m.w};
    float acc = 0.0f;
#pragma unroll
    for (int w = 0; w < 4; ++w) {
#pragma unroll
      for (int hc = 0; hc < 8; ++hc) {
        float4 wv = *(const float4*)&sW2[o][w * 32 + hc * 4];
        float vv[4] = {wv.x, wv.y, wv.z, wv.w};
#pragma unroll
        for (int bb = 0; bb < 4; ++bb) {
          float val = ((mw[w] >> (hc * 4 + bb)) & 1u) ? vv[bb] : 0.0f;
          acc = acc + val;
        }
      }
    }
    float c2 = acc + bias;
    float reset = (mem2 > 1.0f) ? 1.0f : 0.0f;
    mem2 = 0.9f * mem2;
    mem2 = mem2 + c2;
    mem2 = mem2 - reset;
    cnt += (mem2 > 1.0f) ? 1 : 0;
  }
  out[row * O_SZ + o] = (float)cnt / 20.0f;
}

extern "C" void kernel_launch(void* const* d_in, const int* in_sizes, int n_in,
                              void* d_out, int out_size, void* d_ws, size_t ws_size,
                              hipStream_t stream) {
  const float* x   = (const float*)d_in[0];  // [8192,784]
  const float* w1  = (const float*)d_in[1];  // [128,784]
  const float* b1  = (const float*)d_in[2];  // [128]
  const float* w2  = (const float*)d_in[3];  // [10,128]
  const float* b2  = (const float*)d_in[4];  // [10]
  float* out  = (float*)d_out;               // [8192,10]
  float*    cur1  = (float*)d_ws;
  uint32_t* masks = (uint32_t*)((char*)d_ws + MASKS_OFF);
  ushort_t* wp    = (ushort_t*)((char*)d_ws + WP_OFF);
  uint32_t* m32   = (uint32_t*)((char*)d_ws + M32_OFF);

  split_w1     <<<dim3(128),   dim3(256), 0, stream>>>(w1, wp);
  spikegen_bits<<<dim3(16000), dim3(256), 0, stream>>>(x, m32);
  gemm1_mfma   <<<dim3(1280),  dim3(256), 0, stream>>>(wp, m32, b1, cur1);
  lif1_spikes  <<<dim3(512),   dim3(256), 0, stream>>>(cur1, masks);
  lif2_seq     <<<dim3(256),   dim3(320), 0, stream>>>(w2, b2, masks, out);
}